// Round 1
// 225.965 us; speedup vs baseline: 1.0071x; 1.0071x over previous
//
#include <hip/hip_runtime.h>
#include <math.h>

// PCEN: x[B=64, C=128, T=4000] fp32.
// smooth[0]=x[0]; smooth[t]=(1-s)*smooth[t-1]+s*x[t], s=0.025
// out = sqrt(x/(smooth+1e-6)^0.98 + 2) - sqrt(2)
//
// One block (256 threads) per channel, coalesced float4 layout (thread t owns
// float4s {t, t+256, t+512, t+768}). KEY CHANGE vs previous version: the EMA
// decay is a compile-time constant, so every chunk's affine coefficient is
// A = (1-s)^4 uniformly (tail chunks are padded with x=0 and scanned normally;
// the scan is causal so the padding never reaches a stored element). This lets
// us:
//   - scan ONLY the offset B with a literal coefficient (1-s)^(4d) per step
//     (28 ds_bpermute instead of 56, no A multiplies),
//   - compose the cross-wave prefix with the literal (1-s)^256 via a
//     wave-uniform branch (15 fma + <=15 broadcast LDS reads, replacing the
//     old 60-iteration predicated loop and the sA table),
//   - get the per-lane exclusive coefficient (1-s)^(4*lane) from one
//     v_exp_f32.
// Epilogue: v_log / v_exp / v_sqrt hardware transcendentals.

constexpr int   TLEN = 4000;
constexpr int   NF4  = 1000;
constexpr int   NTH  = 256;
constexpr float S_C  = 0.025f;
constexpr float A_1  = 1.0f - S_C;

constexpr float fpow(float b, int n) {
    float r = 1.0f;
    for (int i = 0; i < n; ++i) r *= b;
    return r;
}
constexpr float A_2  = fpow(A_1, 2);
constexpr float A_3  = fpow(A_1, 3);
constexpr float A256 = fpow(A_1, 256);   // one full wave-segment (64 chunks * 4)

// 4*log2(1-s): per-lane exclusive coefficient is exp2(lane * L2A4)
constexpr float L2A4 = -0.14610359f;

constexpr float ALPHA = 0.98f;
constexpr float EPS_C = 1e-6f;
constexpr float SQRT2 = 1.41421356237309515f;

__device__ __forceinline__ float pcen_elem(float x, float sm) {
    float t = sm + EPS_C;
    float p = __builtin_amdgcn_exp2f(-ALPHA * __builtin_amdgcn_logf(t)); // t^-alpha
    float y = fmaf(x, p, 2.0f);
    return __builtin_amdgcn_sqrtf(y) - SQRT2;
}

__global__ __launch_bounds__(NTH) void pcen_kernel(const float* __restrict__ x,
                                                   float* __restrict__ out) {
    const int    tid  = threadIdx.x;
    const int    lane = tid & 63;
    const int    wv   = tid >> 6;
    const size_t base = (size_t)blockIdx.x * TLEN;

    const float4* __restrict__ x4 = (const float4*)(x + base);
    float4*       __restrict__ o4 = (float4*)(out + base);

    // ---- coalesced load: 4 lane-dense float4 loads; tail padded with 0 ----
    float4 v[4];
    bool   act[4];
#pragma unroll
    for (int k = 0; k < 4; ++k) {
        int f4 = tid + NTH * k;
        act[k] = (f4 < NF4);
        v[k]   = act[k] ? x4[f4] : make_float4(0.f, 0.f, 0.f, 0.f);
    }

    // ---- per-mini-chunk offset B (coefficient is uniformly A_1^4) ----
    // chunk value from entering sm: (A_1^4)*sm + B,
    // B = A_1^3*b0 + s*(A_1^2*x1 + A_1*x2 + x3);  b0 = s*x0 (or x0 at t=0)
    float B[4];
#pragma unroll
    for (int k = 0; k < 4; ++k) {
        float4 r  = v[k];
        float  b0 = (tid == 0 && k == 0) ? r.x : S_C * r.x;  // smooth[0]=x[0]
        B[k] = fmaf(A_3, b0, S_C * fmaf(A_2, r.y, fmaf(A_1, r.z, r.w)));
    }

    // ---- 4 interleaved inclusive wave scans over B only ----
    // At step d, the composing lane's accumulated A is the LITERAL A_1^(4d).
    constexpr float CD[6] = { fpow(A_1, 4),  fpow(A_1, 8),   fpow(A_1, 16),
                              fpow(A_1, 32), fpow(A_1, 64),  fpow(A_1, 128) };
#pragma unroll
    for (int s = 0; s < 6; ++s) {
        const int   d = 1 << s;
        const float c = CD[s];
        float Bp[4];
#pragma unroll
        for (int k = 0; k < 4; ++k) Bp[k] = __shfl_up(B[k], d);
        const bool ok = (lane >= d);
#pragma unroll
        for (int k = 0; k < 4; ++k) B[k] = fmaf(c, ok ? Bp[k] : 0.0f, B[k]);
    }

    // ---- wave totals -> LDS (16 B values, m = 4*seg + wave) ----
    __shared__ float sB[16];
    if (lane == 63) {
#pragma unroll
        for (int k = 0; k < 4; ++k) sB[4 * k + wv] = B[k];
    }
    __syncthreads();

    // ---- entering prefix per (wave, segment): chain with literal A256 ----
    // E(k) composes wave totals m < 4k+wv; wave-uniform branch, straight-line.
    float E0, E1, E2, E3;
    {
        float e = 0.0f;
#define CH(m) e = fmaf(A256, e, sB[m]);
        if (wv == 0) {
            E0 = e;
            CH(0) CH(1) CH(2)  E1 = fmaf(A256, e, sB[3]);  CH(3)
            CH(4) CH(5) CH(6)  E2 = fmaf(A256, e, sB[7]);  CH(7)
            CH(8) CH(9) CH(10) E3 = fmaf(A256, e, sB[11]);
        } else if (wv == 1) {
            CH(0)  E0 = e;
            CH(1) CH(2) CH(3)  CH(4)  E1 = e;
            CH(5) CH(6) CH(7)  CH(8)  E2 = e;
            CH(9) CH(10) CH(11) CH(12) E3 = e;
        } else if (wv == 2) {
            CH(0) CH(1)  E0 = e;
            CH(2) CH(3) CH(4) CH(5)   E1 = e;
            CH(6) CH(7) CH(8) CH(9)   E2 = e;
            CH(10) CH(11) CH(12) CH(13) E3 = e;
        } else {
            CH(0) CH(1) CH(2)  E0 = e;
            CH(3) CH(4) CH(5) CH(6)   E1 = e;
            CH(7) CH(8) CH(9) CH(10)  E2 = e;
            CH(11) CH(12) CH(13) CH(14) E3 = e;
        }
#undef CH
    }
    const float E[4] = { E0, E1, E2, E3 };

    // ---- per-lane exclusive coefficient A_1^(4*lane) via one v_exp_f32 ----
    const float Al = __builtin_amdgcn_exp2f((float)lane * L2A4);

    // ---- exclusive prefix, replay, epilogue, dense store ----
#pragma unroll
    for (int k = 0; k < 4; ++k) {
        float Bi = __shfl_up(B[k], 1);
        if (lane == 0) Bi = 0.0f;
        float sm = fmaf(Al, E[k], Bi);           // smoothed value entering chunk

        float4 r  = v[k];
        float  b0 = (tid == 0 && k == 0) ? r.x : S_C * r.x;
        float  s0 = fmaf(A_1, sm, b0);
        float  s1 = fmaf(A_1, s0, S_C * r.y);
        float  s2 = fmaf(A_1, s1, S_C * r.z);
        float  s3 = fmaf(A_1, s2, S_C * r.w);

        float4 o;
        o.x = pcen_elem(r.x, s0);
        o.y = pcen_elem(r.y, s1);
        o.z = pcen_elem(r.z, s2);
        o.w = pcen_elem(r.w, s3);

        int f4 = tid + NTH * k;
        if (act[k]) o4[f4] = o;
    }
}

extern "C" void kernel_launch(void* const* d_in, const int* in_sizes, int n_in,
                              void* d_out, int out_size, void* d_ws, size_t ws_size,
                              hipStream_t stream) {
    const float* x   = (const float*)d_in[0];
    float*       out = (float*)d_out;
    const int nch    = in_sizes[0] / TLEN;   // 8192 channels
    pcen_kernel<<<nch, NTH, 0, stream>>>(x, out);
}